// Round 4
// baseline (122.007 us; speedup 1.0000x reference)
//
#include <hip/hip_runtime.h>

namespace {

constexpr int Tt = 32;    // frames (t)
constexpr int Ss = 784;   // floats per row (h*w)

// ---------------------------------------------------------------------------
// Kernel 1: per-(b,c) Gram.  part[bc][q*32+k] = sum_s x[bc][q][s]*x[bc][k][s]
// 1024 blocks x 512 threads (8 waves). 2 chunks of 98 float4 cols staged in an
// XOR-swizzled LDS tile [32][104] float4 (53 KB) -> 2 blocks/CU, 16 waves.
// Register tile 8x4 per thread: lane = (g<<5)|(ty<<3)|tx ; q rows 8ty+i,
// k rows 4tx+jj ; col-groups g in {0,1} own cols 2m+g. Per col-unit:
// 12 ds_read_b128 for 128 FMAs (2x fewer LDS instrs/FLOP than 4x4).
// Swizzle col' = col ^ 2*((row>>3)&3): a-reads conflict-free, b-reads 2-way.
// g-partials summed via __shfl_xor 32 (VALU pipe, not LDS).
// ---------------------------------------------------------------------------
__global__ __launch_bounds__(512) void gram_partial(const float* __restrict__ x,
                                                    float* __restrict__ part) {
  const int bc = blockIdx.x;                       // b*64 + c
  const float* __restrict__ xb = x + (size_t)bc * (Tt * Ss);
  const int tid  = threadIdx.x;
  const int w    = tid >> 6;      // wave 0..7
  const int lane = tid & 63;
  const int g    = lane >> 5;     // col-group 0..1
  const int ty   = (lane >> 3) & 3;   // q-block 0..3 (rows 8ty..8ty+7)
  const int tx   = lane & 7;          // k-block 0..7 (rows 4tx..4tx+3)

  __shared__ float4 tile[32][104];    // 53248 B; aliased as mtmp after compute

  float acc[8][4] = {};

  for (int ch = 0; ch < 2; ++ch) {
    // stage 32 rows x 98 float4 (1568 B contiguous per row)
    for (int f = tid; f < 3136; f += 512) {
      const int row = f / 98;
      const int c   = f - row * 98;
      const float4 v = *reinterpret_cast<const float4*>(xb + row * Ss + ch * 392 + 4 * c);
      tile[row][c ^ (2 * ((row >> 3) & 3))] = v;
    }
    __syncthreads();

    for (int m = w; m < 49; m += 8) {
      const int c = 2 * m + g;
      float4 a4[8];
#pragma unroll
      for (int i = 0; i < 8; ++i) a4[i] = tile[8 * ty + i][c ^ (2 * ty)];
#pragma unroll
      for (int jj = 0; jj < 4; ++jj) {
        const int row = 4 * tx + jj;
        const float4 b4 = tile[row][c ^ (2 * (tx >> 1))];
#pragma unroll
        for (int i = 0; i < 8; ++i)
          acc[i][jj] += a4[i].x * b4.x + a4[i].y * b4.y +
                        a4[i].z * b4.z + a4[i].w * b4.w;
      }
    }
    __syncthreads();
  }

  // sum the two col-groups (lane ^ 32) on the VALU pipe
#pragma unroll
  for (int i = 0; i < 8; ++i)
#pragma unroll
    for (int jj = 0; jj < 4; ++jj)
      acc[i][jj] += __shfl_xor(acc[i][jj], 32, 64);

  // per-wave partials into LDS (aliases tile; all tile reads complete)
  float* mtmpf = reinterpret_cast<float*>(tile);
  if (g == 0) {
    float4* mtmp4 = reinterpret_cast<float4*>(mtmpf);
#pragma unroll
    for (int i = 0; i < 8; ++i) {
      float4 vv;
      vv.x = acc[i][0]; vv.y = acc[i][1]; vv.z = acc[i][2]; vv.w = acc[i][3];
      mtmp4[w * 256 + (8 * ty + i) * 8 + tx] = vv;
    }
  }
  __syncthreads();

  float* __restrict__ po = part + (size_t)bc * 1024;
#pragma unroll
  for (int t = 0; t < 2; ++t) {
    const int e = tid + 512 * t;
    float s = 0.f;
#pragma unroll
    for (int ww = 0; ww < 8; ++ww) s += mtmpf[ww * 1024 + e];
    po[e] = s;
  }
}

// ---------------------------------------------------------------------------
// Kernel 2: reduce partials over c.  msum[b][e] = sum_c part[b*64+c][e]
// ---------------------------------------------------------------------------
__global__ __launch_bounds__(256) void reduce_c(const float* __restrict__ part,
                                                float* __restrict__ msum) {
  const int bid = blockIdx.x;                // 0..63
  const int b   = bid >> 2;
  const int e   = (bid & 3) * 256 + threadIdx.x;   // 0..1023
  const float* __restrict__ p = part + (size_t)b * 64 * 1024 + e;
  float s0 = 0.f, s1 = 0.f, s2 = 0.f, s3 = 0.f;
#pragma unroll
  for (int c = 0; c < 64; c += 4) {
    s0 += p[(size_t)(c + 0) * 1024];
    s1 += p[(size_t)(c + 1) * 1024];
    s2 += p[(size_t)(c + 2) * 1024];
    s3 += p[(size_t)(c + 3) * 1024];
  }
  msum[b * 1024 + e] = (s0 + s1) + (s2 + s3);
}

// ---------------------------------------------------------------------------
// Kernel 3: softmax over the BATCH axis + transpose to [k][q]-major.
// ---------------------------------------------------------------------------
__global__ __launch_bounds__(256) void softmax_b(const float* __restrict__ msum,
                                                 float* __restrict__ mt) {
  const int e = blockIdx.x * 256 + threadIdx.x;    // q*32 + k
  float l[16];
  float mx = -3.4e38f;
#pragma unroll
  for (int b = 0; b < 16; ++b) {
    l[b] = msum[b * 1024 + e];
    mx = fmaxf(mx, l[b]);
  }
  float s = 0.f;
#pragma unroll
  for (int b = 0; b < 16; ++b) {
    l[b] = expf(l[b] - mx);
    s += l[b];
  }
  const float inv = 1.f / s;
  const int et = (e & 31) * 32 + (e >> 5);         // k*32 + q
#pragma unroll
  for (int b = 0; b < 16; ++b) mt[b * 1024 + et] = l[b] * inv;
}

// ---------------------------------------------------------------------------
// Kernel 4: PV.  out[bc][q][s] = sum_k mt[b][k*32+q] * xv[bc][k][s]
// 4096 blocks = bc*4 + s-chunk; 256 threads = 4 waves (q-groups of 8).
// NO LDS: m-coefficients are wave-uniform -> readfirstlane'd base + direct
// global reads (scalar pipe, L2-hot 64 KB). xv streamed with explicit 4-deep
// double-buffered float4 staging (va/vb) -> ~3 KB in flight per wave.
// ---------------------------------------------------------------------------
__global__ __launch_bounds__(256) void pv(const float* __restrict__ xv,
                                          const float* __restrict__ mt,
                                          float* __restrict__ out) {
  const int gbl   = blockIdx.x;               // bc*4 + chunk
  const int bc    = gbl >> 2;
  const int chunk = gbl & 3;
  const int b     = bc >> 6;
  const float* __restrict__ xvb = xv + (size_t)bc * (Tt * Ss) + chunk * 196;
  float* __restrict__ ob        = out + (size_t)bc * (Tt * Ss) + chunk * 196;

  const int tid  = threadIdx.x;
  const int w    = tid >> 6;
  const int lane = tid & 63;
  const int q0   = __builtin_amdgcn_readfirstlane(8 * w);
  const int moff = __builtin_amdgcn_readfirstlane(b * 1024 + q0);
  const float* __restrict__ mrow = mt + moff;     // mrow[k*32 + r], uniform

  if (lane < 49) {
    const float* __restrict__ src = xvb + 4 * lane;
    float4 acc[8] = {};
    float4 va[4], vb4[4];
#pragma unroll
    for (int t = 0; t < 4; ++t)
      va[t] = *reinterpret_cast<const float4*>(src + (size_t)t * Ss);

#pragma unroll
    for (int kc = 0; kc < 4; ++kc) {
      // prefetch next 4 k-rows (k = 8kc+4 .. 8kc+7; always in range)
#pragma unroll
      for (int t = 0; t < 4; ++t)
        vb4[t] = *reinterpret_cast<const float4*>(src + (size_t)(8 * kc + 4 + t) * Ss);
      // consume va (k = 8kc .. 8kc+3)
#pragma unroll
      for (int t = 0; t < 4; ++t) {
        const int k = 8 * kc + t;
#pragma unroll
        for (int r = 0; r < 8; ++r) {
          const float m = mrow[k * 32 + r];
          acc[r].x += m * va[t].x; acc[r].y += m * va[t].y;
          acc[r].z += m * va[t].z; acc[r].w += m * va[t].w;
        }
      }
      // prefetch following 4 k-rows into va
      if (kc < 3) {
#pragma unroll
        for (int t = 0; t < 4; ++t)
          va[t] = *reinterpret_cast<const float4*>(src + (size_t)(8 * kc + 8 + t) * Ss);
      }
      // consume vb4 (k = 8kc+4 .. 8kc+7)
#pragma unroll
      for (int t = 0; t < 4; ++t) {
        const int k = 8 * kc + 4 + t;
#pragma unroll
        for (int r = 0; r < 8; ++r) {
          const float m = mrow[k * 32 + r];
          acc[r].x += m * vb4[t].x; acc[r].y += m * vb4[t].y;
          acc[r].z += m * vb4[t].z; acc[r].w += m * vb4[t].w;
        }
      }
    }

#pragma unroll
    for (int r = 0; r < 8; ++r)
      *reinterpret_cast<float4*>(ob + (size_t)(q0 + r) * Ss + 4 * lane) = acc[r];
  }
}

}  // namespace

extern "C" void kernel_launch(void* const* d_in, const int* in_sizes, int n_in,
                              void* d_out, int out_size, void* d_ws, size_t ws_size,
                              hipStream_t stream) {
  const float* x  = (const float*)d_in[0];
  const float* xv = (const float*)d_in[1];
  float* out = (float*)d_out;

  // workspace (fp32), ~4.2 MiB total:
  float* part = (float*)d_ws;            // 1024 x 1024
  float* msum = part + 1024 * 1024;      // 16 x 1024
  float* mt   = msum + 16 * 1024;        // 16 x 1024 (k-major softmax weights)

  gram_partial<<<dim3(1024), dim3(512), 0, stream>>>(x, part);
  reduce_c<<<dim3(64), dim3(256), 0, stream>>>(part, msum);
  softmax_b<<<dim3(4), dim3(256), 0, stream>>>(msum, mt);
  pv<<<dim3(4096), dim3(256), 0, stream>>>(xv, mt, out);
}